// Round 4
// baseline (272.214 us; speedup 1.0000x reference)
//
#include <hip/hip_runtime.h>
#include <math.h>

// CausalSemanticGrouping: key [B,N,D] fp32, slot_embed [K,D] fp32
#define BB 64
#define NN 1024
#define DD 512
#define KK 64
#define CC 1088           // K + N
#define NCT 17            // C / 64
#define INVT 14.285714285714286f   // 1 / 0.07

// d_out: out [B,K,D] fp32 then dots [B,K,C] fp32.
// d_ws (floats): rslot [64] | denomP [B*K*34] | Sp [K*D] u32 | Pp [B*K*C] u32
//   All regions fully written before read -> no zero-init required.

typedef __bf16 bf16_t;
typedef __bf16 bf16x4 __attribute__((ext_vector_type(4)));
typedef __bf16 bf16x8 __attribute__((ext_vector_type(8)));
typedef float f32x16 __attribute__((ext_vector_type(16)));

__device__ __forceinline__ void gload16(const void* src, void* lds) {
    __builtin_amdgcn_global_load_lds(
        (const __attribute__((address_space(1))) void*)src,
        (__attribute__((address_space(3))) void*)lds, 16, 0, 0);
}
__device__ __forceinline__ float waveReduceSum(float v) {
    #pragma unroll
    for (int off = 32; off > 0; off >>= 1) v += __shfl_down(v, off, 64);
    return v;
}
__device__ __forceinline__ void split4(float4 x, bf16x4& hi, bf16x4& lo) {
    float v[4] = {x.x, x.y, x.z, x.w};
    #pragma unroll
    for (int j = 0; j < 4; j++) {
        __bf16 h = (__bf16)v[j];
        hi[j] = h;
        lo[j] = (__bf16)(v[j] - (float)h);
    }
}
__device__ __forceinline__ bf16x8 cat8(bf16x4 a, bf16x4 b) {
    union { bf16x4 h[2]; bf16x8 v; } u;
    u.h[0] = a; u.h[1] = b;
    return u.v;
}
__device__ __forceinline__ unsigned packhl(__bf16 h, __bf16 l) {
    return ((unsigned)__builtin_bit_cast(unsigned short, h) << 16)
         | (unsigned)__builtin_bit_cast(unsigned short, l);
}
__device__ __forceinline__ void unpack4(uint4 w, bf16x4& hi, bf16x4& lo) {
    unsigned h01 = (w.x >> 16) | (w.y & 0xffff0000u);
    unsigned h23 = (w.z >> 16) | (w.w & 0xffff0000u);
    unsigned l01 = (w.x & 0xffffu) | (w.y << 16);
    unsigned l23 = (w.z & 0xffffu) | (w.w << 16);
    uint2 hw = {h01, h23}, lw = {l01, l23};
    hi = __builtin_bit_cast(bf16x4, hw);
    lo = __builtin_bit_cast(bf16x4, lw);
}

// slot pre-split + slot norms. grid 64 x 64.
__global__ __launch_bounds__(64) void k_prep(const float* __restrict__ slot,
                                             unsigned* __restrict__ Sp,
                                             float* __restrict__ rslot) {
    int k = blockIdx.x, lane = threadIdx.x;
    const float4* row = (const float4*)(slot + (size_t)k * DD);
    uint4* orow = (uint4*)(Sp + (size_t)k * DD);
    float s = 0.f;
    #pragma unroll
    for (int i = 0; i < 2; i++) {
        float4 v = row[lane + i * 64];
        s += v.x * v.x + v.y * v.y + v.z * v.z + v.w * v.w;
        bf16x4 h, l;
        split4(v, h, l);
        uint4 wv;
        wv.x = packhl(h[0], l[0]); wv.y = packhl(h[1], l[1]);
        wv.z = packhl(h[2], l[2]); wv.w = packhl(h[3], l[3]);
        orow[lane + i * 64] = wv;
    }
    s = waveReduceSum(s);
    if (lane == 0) rslot[k] = 1.0f / fmaxf(sqrtf(s), 1e-12f);
}

// ct = blockIdx.x + 1 (key columns). A from Sp regs (loaded pre-barrier),
// B staged via global_load_lds dbuf. Zero vmem waits in MFMA phase.
__global__ __launch_bounds__(256, 4) void k_dots(const float* __restrict__ key,
                                                 const unsigned* __restrict__ Sp,
                                                 const float* __restrict__ rslot,
                                                 float* __restrict__ dots,
                                                 unsigned* __restrict__ Pp,
                                                 float* __restrict__ denomP) {
    __shared__ __align__(16) float Bt[2][64][64];
    __shared__ float sA[64], srB[64];
    const int b = blockIdx.y, ct = blockIdx.x + 1;
    const int tid = threadIdx.x;
    const int w = tid >> 6, lane = tid & 63;
    const int mw = (w >> 1) * 32, nw = (w & 1) * 32;
    const int half = lane >> 5;
    const int rq = tid >> 4, p = tid & 15;
    const int pswz = p ^ rq;

    const float* srcbase =
        key + ((size_t)b * NN + (size_t)(ct - 1) * 64 + rq) * DD + pswz * 4;
    const int brow = nw + (lane & 31);
    const int bsw = lane & 15;

    if (tid < 64) sA[tid] = rslot[tid];

    const uint4* aP = (const uint4*)(Sp + (size_t)(mw + (lane & 31)) * DD);
    uint4 areg[8];
    f32x16 acc = {};
    float sq = 0.f;

    auto loadA = [&](int t) {
        #pragma unroll
        for (int q = 0; q < 4; q++) {
            areg[2 * q]     = aP[t * 16 + q * 4 + half * 2];
            areg[2 * q + 1] = aP[t * 16 + q * 4 + half * 2 + 1];
        }
    };
    auto stageB = [&](int buf, int t) {
        char* l = (char*)&Bt[buf][0][0] + w * 1024;
        const float* s = srcbase + t * 64;
        #pragma unroll
        for (int i = 0; i < 4; i++)
            gload16(s + (size_t)i * 16 * DD, l + i * 4096);
    };

    loadA(0);
    __builtin_amdgcn_sched_barrier(0);
    stageB(0, 0);
    __syncthreads();

    for (int t = 0; t < 8; t++) {
        const int cur = t & 1;
        if (t + 1 < 8) stageB(cur ^ 1, t + 1);
        __builtin_amdgcn_sched_barrier(0);
        #pragma unroll
        for (int q = 0; q < 4; q++) {
            bf16x4 h0, l0, h1, l1;
            unpack4(areg[2 * q], h0, l0);
            unpack4(areg[2 * q + 1], h1, l1);
            bf16x8 ah = cat8(h0, h1), al = cat8(l0, l1);
            const int s0 = q * 4 + half * 2;
            float4 b0 = *(const float4*)&Bt[cur][brow][((s0) ^ bsw) << 2];
            float4 b1 = *(const float4*)&Bt[cur][brow][((s0 + 1) ^ bsw) << 2];
            sq += b0.x*b0.x + b0.y*b0.y + b0.z*b0.z + b0.w*b0.w
                + b1.x*b1.x + b1.y*b1.y + b1.z*b1.z + b1.w*b1.w;
            split4(b0, h0, l0); split4(b1, h1, l1);
            bf16x8 bh = cat8(h0, h1), bl = cat8(l0, l1);
            acc = __builtin_amdgcn_mfma_f32_32x32x16_bf16(ah, bh, acc, 0, 0, 0);
            acc = __builtin_amdgcn_mfma_f32_32x32x16_bf16(ah, bl, acc, 0, 0, 0);
            acc = __builtin_amdgcn_mfma_f32_32x32x16_bf16(al, bh, acc, 0, 0, 0);
        }
        if (t + 1 < 8) loadA(t + 1);
        __syncthreads();
    }

    float st = sq + __shfl_xor(sq, 32, 64);
    if (w < 2 && lane < 32)
        srB[(w & 1) * 32 + lane] = 1.0f / fmaxf(sqrtf(st), 1e-12f);
    __syncthreads();

    const int n = nw + (lane & 31);
    const int c = ct * 64 + n;
    const float rn = srB[n];
    #pragma unroll
    for (int reg = 0; reg < 16; reg++) {
        int m = mw + (reg & 3) + 8 * (reg >> 2) + 4 * half;
        float v = acc[reg] * sA[m] * rn;
        dots[((size_t)b * KK + m) * CC + c] = v;
        float e = __expf(v * INVT);             // c >= KK always here
        __bf16 hh = (__bf16)e;
        __bf16 ll = (__bf16)(e - (float)hh);
        Pp[((size_t)b * KK + m) * CC + c] = packhl(hh, ll);
        #pragma unroll
        for (int off = 16; off > 0; off >>= 1) e += __shfl_xor(e, off, 64);
        if ((lane & 31) == 0)
            denomP[((size_t)b * KK + m) * 34 + ct * 2 + (w & 1)] = e;
    }
}

// ct == 0 specialization: B-rows are slot rows (f32 from slot), norms = rslot.
__global__ __launch_bounds__(256, 4) void k_dots0(const float* __restrict__ slot,
                                                  const unsigned* __restrict__ Sp,
                                                  const float* __restrict__ rslot,
                                                  float* __restrict__ dots,
                                                  unsigned* __restrict__ Pp,
                                                  float* __restrict__ denomP) {
    __shared__ __align__(16) float Bt[2][64][64];
    __shared__ float sA[64];
    const int b = blockIdx.y;
    const int tid = threadIdx.x;
    const int w = tid >> 6, lane = tid & 63;
    const int mw = (w >> 1) * 32, nw = (w & 1) * 32;
    const int half = lane >> 5;
    const int rq = tid >> 4, p = tid & 15;
    const int pswz = p ^ rq;

    const float* srcbase = slot + (size_t)rq * DD + pswz * 4;
    const int brow = nw + (lane & 31);
    const int bsw = lane & 15;

    if (tid < 64) sA[tid] = rslot[tid];

    const uint4* aP = (const uint4*)(Sp + (size_t)(mw + (lane & 31)) * DD);
    uint4 areg[8];
    f32x16 acc = {};

    auto loadA = [&](int t) {
        #pragma unroll
        for (int q = 0; q < 4; q++) {
            areg[2 * q]     = aP[t * 16 + q * 4 + half * 2];
            areg[2 * q + 1] = aP[t * 16 + q * 4 + half * 2 + 1];
        }
    };
    auto stageB = [&](int buf, int t) {
        char* l = (char*)&Bt[buf][0][0] + w * 1024;
        const float* s = srcbase + t * 64;
        #pragma unroll
        for (int i = 0; i < 4; i++)
            gload16(s + (size_t)i * 16 * DD, l + i * 4096);
    };

    loadA(0);
    __builtin_amdgcn_sched_barrier(0);
    stageB(0, 0);
    __syncthreads();

    for (int t = 0; t < 8; t++) {
        const int cur = t & 1;
        if (t + 1 < 8) stageB(cur ^ 1, t + 1);
        __builtin_amdgcn_sched_barrier(0);
        #pragma unroll
        for (int q = 0; q < 4; q++) {
            bf16x4 h0, l0, h1, l1;
            unpack4(areg[2 * q], h0, l0);
            unpack4(areg[2 * q + 1], h1, l1);
            bf16x8 ah = cat8(h0, h1), al = cat8(l0, l1);
            const int s0 = q * 4 + half * 2;
            float4 b0 = *(const float4*)&Bt[cur][brow][((s0) ^ bsw) << 2];
            float4 b1 = *(const float4*)&Bt[cur][brow][((s0 + 1) ^ bsw) << 2];
            split4(b0, h0, l0); split4(b1, h1, l1);
            bf16x8 bh = cat8(h0, h1), bl = cat8(l0, l1);
            acc = __builtin_amdgcn_mfma_f32_32x32x16_bf16(ah, bh, acc, 0, 0, 0);
            acc = __builtin_amdgcn_mfma_f32_32x32x16_bf16(ah, bl, acc, 0, 0, 0);
            acc = __builtin_amdgcn_mfma_f32_32x32x16_bf16(al, bh, acc, 0, 0, 0);
        }
        if (t + 1 < 8) loadA(t + 1);
        __syncthreads();
    }

    const int n = nw + (lane & 31);
    const int c = n;
    const float rn = sA[n];
    #pragma unroll
    for (int reg = 0; reg < 16; reg++) {
        int m = mw + (reg & 3) + 8 * (reg >> 2) + 4 * half;
        float v = acc[reg] * sA[m] * rn;
        dots[((size_t)b * KK + m) * CC + c] = v;
        float e = (c < m) ? __expf(v * INVT) : 0.0f;
        __bf16 hh = (__bf16)e;
        __bf16 ll = (__bf16)(e - (float)hh);
        Pp[((size_t)b * KK + m) * CC + c] = packhl(hh, ll);
        #pragma unroll
        for (int off = 16; off > 0; off >>= 1) e += __shfl_xor(e, off, 64);
        if ((lane & 31) == 0)
            denomP[((size_t)b * KK + m) * 34 + (w & 1)] = e;
    }
}

// out = (P x V) * invden. P fragments from Pp direct to regs (L2-hot via XCD
// swizzle), loaded pre-barrier; V staged f32 via global_load_lds dbuf.
__global__ __launch_bounds__(256, 4) void k_out(const float* __restrict__ key,
                                                const float* __restrict__ slot,
                                                const unsigned* __restrict__ Pp,
                                                const float* __restrict__ denomP,
                                                float* __restrict__ out) {
    __shared__ __align__(16) float Vt[2][64][64];
    __shared__ float sd[64];
    const int flat = blockIdx.x + blockIdx.y * 8;
    const int q8 = flat >> 6, s = flat & 63;
    const int b = (q8 << 3) | (s & 7);
    const int d0 = (s >> 3) * 64;
    const int tid = threadIdx.x;
    const int w = tid >> 6, lane = tid & 63;
    const int mw = (w >> 1) * 32, nw = (w & 1) * 32;
    const int half = lane >> 5;
    const int rq = tid >> 4, p = tid & 15;
    const int pswz = p ^ rq;

    if (tid < 64) {
        const float* dp = denomP + ((size_t)b * KK + tid) * 34;
        float ss = 0.f;
        #pragma unroll
        for (int j = 0; j < 34; j++) ss += dp[j];
        sd[tid] = 1.0f / (ss * (1.0f + 1e-7f));
    }

    const int arow = mw + (lane & 31);
    const uint4* pbase = (const uint4*)(Pp + ((size_t)b * KK + arow) * CC);
    const int d = nw + (lane & 31);
    const int dslot = d >> 2, dword = d & 3;

    uint4 preg[8];
    f32x16 acc = {};

    auto loadP = [&](int t) {
        #pragma unroll
        for (int q = 0; q < 4; q++) {
            preg[2 * q]     = pbase[t * 16 + q * 4 + half * 2];
            preg[2 * q + 1] = pbase[t * 16 + q * 4 + half * 2 + 1];
        }
    };
    auto stageV = [&](int buf, int t) {
        char* lv = (char*)&Vt[buf][0][0] + w * 1024;
        const float* vb = (t == 0)
            ? (slot + (size_t)rq * DD + d0 + pswz * 4)
            : (key + ((size_t)b * NN + (size_t)(t - 1) * 64 + rq) * DD + d0 + pswz * 4);
        #pragma unroll
        for (int i = 0; i < 4; i++)
            gload16(vb + (size_t)i * 16 * DD, lv + i * 4096);
    };

    loadP(0);
    __builtin_amdgcn_sched_barrier(0);
    stageV(0, 0);
    __syncthreads();

    for (int t = 0; t < NCT; t++) {
        const int cur = t & 1;
        if (t + 1 < NCT) stageV(cur ^ 1, t + 1);
        __builtin_amdgcn_sched_barrier(0);
        #pragma unroll
        for (int q = 0; q < 4; q++) {
            bf16x4 h0, l0, h1, l1;
            unpack4(preg[2 * q], h0, l0);
            unpack4(preg[2 * q + 1], h1, l1);
            bf16x8 ah = cat8(h0, h1), al = cat8(l0, l1);
            bf16x8 vh, vl;
            #pragma unroll
            for (int j = 0; j < 8; j++) {
                const int rv = q * 16 + half * 8 + j;
                float f = Vt[cur][rv][((dslot ^ (rv & 15)) << 2) + dword];
                __bf16 fh = (__bf16)f;
                vh[j] = fh;
                vl[j] = (__bf16)(f - (float)fh);
            }
            acc = __builtin_amdgcn_mfma_f32_32x32x16_bf16(ah, vh, acc, 0, 0, 0);
            acc = __builtin_amdgcn_mfma_f32_32x32x16_bf16(ah, vl, acc, 0, 0, 0);
            acc = __builtin_amdgcn_mfma_f32_32x32x16_bf16(al, vh, acc, 0, 0, 0);
        }
        if (t + 1 < NCT) loadP(t + 1);
        __syncthreads();
    }

    const int dd = d0 + d;
    #pragma unroll
    for (int reg = 0; reg < 16; reg++) {
        int m = mw + (reg & 3) + 8 * (reg >> 2) + 4 * half;
        out[((size_t)b * KK + m) * DD + dd] = acc[reg] * sd[m];
    }
}

extern "C" void kernel_launch(void* const* d_in, const int* in_sizes, int n_in,
                              void* d_out, int out_size, void* d_ws, size_t ws_size,
                              hipStream_t stream) {
    const float* key  = (const float*)d_in[0];   // [B, N, D]
    const float* slot = (const float*)d_in[1];   // [K, D]
    float* out  = (float*)d_out;                        // [B, K, D]
    float* dots = out + (size_t)BB * KK * DD;           // [B, K, C]
    float* ws = (float*)d_ws;
    float* rslot = ws;                                  // [64]
    float* denomP = ws + 64;                            // [B*K*34]
    unsigned* Sp = (unsigned*)(ws + 64 + (size_t)BB * KK * 34);   // [K*D]
    unsigned* Pp = Sp + (size_t)KK * DD;                          // [B*K*C]

    k_prep<<<dim3(KK), dim3(64), 0, stream>>>(slot, Sp, rslot);
    k_dots0<<<dim3(1, BB), dim3(256), 0, stream>>>(slot, Sp, rslot, dots, Pp, denomP);
    k_dots<<<dim3(NCT - 1, BB), dim3(256), 0, stream>>>(key, Sp, rslot, dots, Pp, denomP);
    k_out<<<dim3(DD / 64, BB), dim3(256), 0, stream>>>(key, slot, Pp, denomP, out);
}

// Round 6
// 261.851 us; speedup vs baseline: 1.0396x; 1.0396x over previous
//
#include <hip/hip_runtime.h>
#include <math.h>

// CausalSemanticGrouping: key [B,N,D] fp32, slot_embed [K,D] fp32
#define BB 64
#define NN 1024
#define DD 512
#define KK 64
#define CC 1088           // K + N
#define NCT 17            // C / 64
#define INVT 14.285714285714286f   // 1 / 0.07

// d_out: out [B,K,D] fp32 then dots [B,K,C] fp32.
// d_ws (floats): rslot [64] | denomP [B*K*34] | Sp [K*D] u32 | Pp [B*K*C] u32
//   All regions fully written before read -> no zero-init required.

typedef __bf16 bf16_t;
typedef __bf16 bf16x4 __attribute__((ext_vector_type(4)));
typedef __bf16 bf16x8 __attribute__((ext_vector_type(8)));
typedef float f32x16 __attribute__((ext_vector_type(16)));

// counted vmem wait: the ONLY waits in the main loops (never vmcnt(0))
#define WAITV(n) asm volatile("s_waitcnt vmcnt(" #n ")" ::: "memory")
#define SCHED_FENCE() __builtin_amdgcn_sched_barrier(0)

__device__ __forceinline__ void gload16(const void* src, void* lds) {
    __builtin_amdgcn_global_load_lds(
        (const __attribute__((address_space(1))) void*)src,
        (__attribute__((address_space(3))) void*)lds, 16, 0, 0);
}
__device__ __forceinline__ float waveReduceSum(float v) {
    #pragma unroll
    for (int off = 32; off > 0; off >>= 1) v += __shfl_down(v, off, 64);
    return v;
}
__device__ __forceinline__ void split4(float4 x, bf16x4& hi, bf16x4& lo) {
    float v[4] = {x.x, x.y, x.z, x.w};
    #pragma unroll
    for (int j = 0; j < 4; j++) {
        __bf16 h = (__bf16)v[j];
        hi[j] = h;
        lo[j] = (__bf16)(v[j] - (float)h);
    }
}
__device__ __forceinline__ bf16x8 cat8(bf16x4 a, bf16x4 b) {
    union { bf16x4 h[2]; bf16x8 v; } u;
    u.h[0] = a; u.h[1] = b;
    return u.v;
}
__device__ __forceinline__ unsigned packhl(__bf16 h, __bf16 l) {
    return ((unsigned)__builtin_bit_cast(unsigned short, h) << 16)
         | (unsigned)__builtin_bit_cast(unsigned short, l);
}
__device__ __forceinline__ void unpack4(uint4 w, bf16x4& hi, bf16x4& lo) {
    unsigned h01 = (w.x >> 16) | (w.y & 0xffff0000u);
    unsigned h23 = (w.z >> 16) | (w.w & 0xffff0000u);
    unsigned l01 = (w.x & 0xffffu) | (w.y << 16);
    unsigned l23 = (w.z & 0xffffu) | (w.w << 16);
    uint2 hw = {h01, h23}, lw = {l01, l23};
    hi = __builtin_bit_cast(bf16x4, hw);
    lo = __builtin_bit_cast(bf16x4, lw);
}

// slot pre-split + slot norms. grid 64 x 64.
__global__ __launch_bounds__(64) void k_prep(const float* __restrict__ slot,
                                             unsigned* __restrict__ Sp,
                                             float* __restrict__ rslot) {
    int k = blockIdx.x, lane = threadIdx.x;
    const float4* row = (const float4*)(slot + (size_t)k * DD);
    uint4* orow = (uint4*)(Sp + (size_t)k * DD);
    float s = 0.f;
    #pragma unroll
    for (int i = 0; i < 2; i++) {
        float4 v = row[lane + i * 64];
        s += v.x * v.x + v.y * v.y + v.z * v.z + v.w * v.w;
        bf16x4 h, l;
        split4(v, h, l);
        uint4 wv;
        wv.x = packhl(h[0], l[0]); wv.y = packhl(h[1], l[1]);
        wv.z = packhl(h[2], l[2]); wv.w = packhl(h[3], l[3]);
        orow[lane + i * 64] = wv;
    }
    s = waveReduceSum(s);
    if (lane == 0) rslot[k] = 1.0f / fmaxf(sqrtf(s), 1e-12f);
}

// dots[b, 0:64, ct*64:+64] via split-bf16 32x32x16 MFMA.
// 3-deep global_load_lds pipeline, raw s_barrier + counted vmcnt (never 0 in
// loop). A fragments from packed Sp in dbuf registers, issued one tile ahead.
// Key norms fused from B fragments. grid (17, B) x 256, 3 blocks/CU.
__global__ __launch_bounds__(256, 3) void k_dots(const float* __restrict__ key,
                                                 const float* __restrict__ slot,
                                                 const unsigned* __restrict__ Sp,
                                                 const float* __restrict__ rslot,
                                                 float* __restrict__ dots,
                                                 unsigned* __restrict__ Pp,
                                                 float* __restrict__ denomP) {
    __shared__ __align__(16) float Bt[3][64][64];   // 48 KB, 3-deep pipeline
    __shared__ float sA[64], srB[64];
    const int b = blockIdx.y, ct = blockIdx.x;
    const int tid = threadIdx.x;
    const int w = tid >> 6, lane = tid & 63;
    const int mw = (w >> 1) * 32, nw = (w & 1) * 32;
    const int half = lane >> 5;
    const int rq = tid >> 4, p = tid & 15;
    const int pswz = p ^ rq;                 // involution within 16-slot granule

    // B source: slot rows (ct==0) or key rows; pre-swizzled column
    const float* srcbase = (ct == 0)
        ? (slot + (size_t)rq * DD + pswz * 4)
        : (key + ((size_t)b * NN + (size_t)(ct - 1) * 64 + rq) * DD + pswz * 4);
    const int brow = nw + (lane & 31);
    const int bsw = lane & 15;

    if (tid < 64) sA[tid] = rslot[tid];      // oldest vmem op; harmless to counts
    SCHED_FENCE();

    const uint4* aP = (const uint4*)(Sp + (size_t)(mw + (lane & 31)) * DD);
    uint4 areg[2][8];
    f32x16 acc = {};
    float sq = 0.f;

    #define LOADA(dst, t)                                              \
        { _Pragma("unroll")                                            \
          for (int q = 0; q < 4; q++) {                                \
              dst[2 * q]     = aP[(t) * 16 + q * 4 + half * 2];        \
              dst[2 * q + 1] = aP[(t) * 16 + q * 4 + half * 2 + 1];    \
          } }
    #define STAGEB(buf, t)                                             \
        { char* l_ = (char*)&Bt[buf][0][0] + w * 1024;                 \
          const float* s_ = srcbase + (t) * 64;                        \
          _Pragma("unroll")                                            \
          for (int i = 0; i < 4; i++)                                  \
              gload16(s_ + (size_t)i * 16 * DD, l_ + i * 4096); }

    // prologue: stage(0), loadA(0), stage(1)  [issue order pinned]
    STAGEB(0, 0);
    SCHED_FENCE();
    LOADA(areg[0], 0);
    SCHED_FENCE();
    STAGEB(1, 1);
    SCHED_FENCE();

    #pragma unroll
    for (int t = 0; t < 8; t++) {
        // wait for stage(t): newer ops = loadA(t)[8] + stage(t+1)[4 if exists]
        if (t < 7) { WAITV(12); } else { WAITV(8); }
        __builtin_amdgcn_s_barrier();
        SCHED_FENCE();
        if (t + 1 < 8) LOADA(areg[(t + 1) & 1], t + 1);
        SCHED_FENCE();
        if (t + 2 < 8) STAGEB((t + 2) % 3, t + 2);
        SCHED_FENCE();
        #pragma unroll
        for (int q = 0; q < 4; q++) {
            bf16x4 h0, l0, h1, l1;
            unpack4(areg[t & 1][2 * q], h0, l0);
            unpack4(areg[t & 1][2 * q + 1], h1, l1);
            bf16x8 ah = cat8(h0, h1), al = cat8(l0, l1);
            const int s0 = q * 4 + half * 2;
            float4 b0 = *(const float4*)&Bt[t % 3][brow][((s0) ^ bsw) << 2];
            float4 b1 = *(const float4*)&Bt[t % 3][brow][((s0 + 1) ^ bsw) << 2];
            sq += b0.x*b0.x + b0.y*b0.y + b0.z*b0.z + b0.w*b0.w
                + b1.x*b1.x + b1.y*b1.y + b1.z*b1.z + b1.w*b1.w;
            split4(b0, h0, l0); split4(b1, h1, l1);
            bf16x8 bh = cat8(h0, h1), bl = cat8(l0, l1);
            acc = __builtin_amdgcn_mfma_f32_32x32x16_bf16(ah, bh, acc, 0, 0, 0);
            acc = __builtin_amdgcn_mfma_f32_32x32x16_bf16(ah, bl, acc, 0, 0, 0);
            acc = __builtin_amdgcn_mfma_f32_32x32x16_bf16(al, bh, acc, 0, 0, 0);
        }
        SCHED_FENCE();
    }
    #undef LOADA
    #undef STAGEB

    // ---- column norms from B fragments (valid for slot AND key tiles) ----
    float st = sq + __shfl_xor(sq, 32, 64);
    if (w < 2 && lane < 32)
        srB[(w & 1) * 32 + lane] = 1.0f / fmaxf(sqrtf(st), 1e-12f);
    __syncthreads();

    // ---- epilogue: scale, write dots + packed P, masked-exp row partials ----
    const int n = nw + (lane & 31);
    const int c = ct * 64 + n;
    const float rn = srB[n];
    #pragma unroll
    for (int reg = 0; reg < 16; reg++) {
        int m = mw + (reg & 3) + 8 * (reg >> 2) + 4 * half;
        float v = acc[reg] * sA[m] * rn;
        dots[((size_t)b * KK + m) * CC + c] = v;
        float e = ((c >= KK) || (c < m)) ? __expf(v * INVT) : 0.0f;
        __bf16 hh = (__bf16)e;
        __bf16 ll = (__bf16)(e - (float)hh);
        Pp[((size_t)b * KK + m) * CC + c] = packhl(hh, ll);
        #pragma unroll
        for (int off = 16; off > 0; off >>= 1) e += __shfl_xor(e, off, 64);
        if ((lane & 31) == 0)
            denomP[((size_t)b * KK + m) * 34 + ct * 2 + (w & 1)] = e;
    }
}

// out = (P x V) * invden. V staged 3-deep via global_load_lds + counted vmcnt;
// P fragments from packed Pp (L2-hot via XCD swizzle) in dbuf registers.
// grid (8, B) x 256, 3 blocks/CU.
__global__ __launch_bounds__(256, 3) void k_out(const float* __restrict__ key,
                                                const float* __restrict__ slot,
                                                const unsigned* __restrict__ Pp,
                                                const float* __restrict__ denomP,
                                                float* __restrict__ out) {
    __shared__ __align__(16) float Vt[3][64][64];   // 48 KB, 3-deep pipeline
    __shared__ float sd[64];
    const int flat = blockIdx.x + blockIdx.y * 8;
    const int q8 = flat >> 6, s = flat & 63;
    const int b = (q8 << 3) | (s & 7);      // 8 d-blocks of one b per XCD
    const int d0 = (s >> 3) * 64;
    const int tid = threadIdx.x;
    const int w = tid >> 6, lane = tid & 63;
    const int mw = (w >> 1) * 32, nw = (w & 1) * 32;
    const int half = lane >> 5;
    const int rq = tid >> 4, p = tid & 15;
    const int pswz = p ^ rq;

    if (tid < 64) {                          // oldest vmem ops; harmless
        const float* dp = denomP + ((size_t)b * KK + tid) * 34;
        float ss = 0.f;
        #pragma unroll
        for (int j = 0; j < 34; j++) ss += dp[j];
        sd[tid] = 1.0f / (ss * (1.0f + 1e-7f));
    }
    SCHED_FENCE();

    const int arow = mw + (lane & 31);
    const uint4* pbase = (const uint4*)(Pp + ((size_t)b * KK + arow) * CC);
    const int d = nw + (lane & 31);
    const int dslot = d >> 2, dword = d & 3;

    uint4 preg[2][8];
    f32x16 acc = {};

    #define LOADP(dst, t)                                              \
        { _Pragma("unroll")                                            \
          for (int q = 0; q < 4; q++) {                                \
              dst[2 * q]     = pbase[(t) * 16 + q * 4 + half * 2];     \
              dst[2 * q + 1] = pbase[(t) * 16 + q * 4 + half * 2 + 1]; \
          } }
    #define STAGEV(buf, t)                                             \
        { char* l_ = (char*)&Vt[buf][0][0] + w * 1024;                 \
          const float* v_ = ((t) == 0)                                 \
              ? (slot + (size_t)rq * DD + d0 + pswz * 4)               \
              : (key + ((size_t)b * NN + (size_t)((t) - 1) * 64 + rq) * DD \
                 + d0 + pswz * 4);                                     \
          _Pragma("unroll")                                            \
          for (int i = 0; i < 4; i++)                                  \
              gload16(v_ + (size_t)i * 16 * DD, l_ + i * 4096); }

    STAGEV(0, 0);
    SCHED_FENCE();
    LOADP(preg[0], 0);
    SCHED_FENCE();
    STAGEV(1, 1);
    SCHED_FENCE();

    #pragma unroll
    for (int t = 0; t < NCT; t++) {
        if (t < NCT - 1) { WAITV(12); } else { WAITV(8); }
        __builtin_amdgcn_s_barrier();
        SCHED_FENCE();
        if (t + 1 < NCT) LOADP(preg[(t + 1) & 1], t + 1);
        SCHED_FENCE();
        if (t + 2 < NCT) STAGEV((t + 2) % 3, t + 2);
        SCHED_FENCE();
        #pragma unroll
        for (int q = 0; q < 4; q++) {
            bf16x4 h0, l0, h1, l1;
            unpack4(preg[t & 1][2 * q], h0, l0);
            unpack4(preg[t & 1][2 * q + 1], h1, l1);
            bf16x8 ah = cat8(h0, h1), al = cat8(l0, l1);
            bf16x8 vh, vl;
            #pragma unroll
            for (int j = 0; j < 8; j++) {
                const int rv = q * 16 + half * 8 + j;
                float f = Vt[t % 3][rv][((dslot ^ (rv & 15)) << 2) + dword];
                __bf16 fh = (__bf16)f;
                vh[j] = fh;
                vl[j] = (__bf16)(f - (float)fh);
            }
            acc = __builtin_amdgcn_mfma_f32_32x32x16_bf16(ah, vh, acc, 0, 0, 0);
            acc = __builtin_amdgcn_mfma_f32_32x32x16_bf16(ah, vl, acc, 0, 0, 0);
            acc = __builtin_amdgcn_mfma_f32_32x32x16_bf16(al, vh, acc, 0, 0, 0);
        }
        SCHED_FENCE();
    }
    #undef LOADP
    #undef STAGEV

    __syncthreads();   // drain before epilogue (loop done; harmless)
    const int dd = d0 + d;
    #pragma unroll
    for (int reg = 0; reg < 16; reg++) {
        int m = mw + (reg & 3) + 8 * (reg >> 2) + 4 * half;
        out[((size_t)b * KK + m) * DD + dd] = acc[reg] * sd[m];
    }
}

extern "C" void kernel_launch(void* const* d_in, const int* in_sizes, int n_in,
                              void* d_out, int out_size, void* d_ws, size_t ws_size,
                              hipStream_t stream) {
    const float* key  = (const float*)d_in[0];   // [B, N, D]
    const float* slot = (const float*)d_in[1];   // [K, D]
    float* out  = (float*)d_out;                        // [B, K, D]
    float* dots = out + (size_t)BB * KK * DD;           // [B, K, C]
    float* ws = (float*)d_ws;
    float* rslot = ws;                                  // [64]
    float* denomP = ws + 64;                            // [B*K*34]
    unsigned* Sp = (unsigned*)(ws + 64 + (size_t)BB * KK * 34);   // [K*D]
    unsigned* Pp = Sp + (size_t)KK * DD;                          // [B*K*C]

    k_prep<<<dim3(KK), dim3(64), 0, stream>>>(slot, Sp, rslot);
    k_dots<<<dim3(NCT, BB), dim3(256), 0, stream>>>(key, slot, Sp, rslot,
                                                    dots, Pp, denomP);
    k_out<<<dim3(DD / 64, BB), dim3(256), 0, stream>>>(key, slot, Pp, denomP, out);
}